// Round 8
// baseline (290.949 us; speedup 1.0000x reference)
//
#include <hip/hip_runtime.h>

// Problem constants (setup_inputs is fixed)
#define BATCH 2
#define NTXT  2048
#define TMED  4
#define MMED  256
#define TM    (TMED * MMED)      // 1024 kv rows per batch
#define DIM   1024
#define NH    16
#define DHD   64
#define KVW   2048               // k|v concatenated width
#define RMAX  256                // max real rows per batch supported

typedef _Float16 f16x8 __attribute__((ext_vector_type(8)));
typedef _Float16 f16x4 __attribute__((ext_vector_type(4)));
typedef float    f32x4 __attribute__((ext_vector_type(4)));

// ---------------------------------------------------------------------------
// find positions of the 1st..5th ones in loc[b,:] (wave 0 only)
// txt_time = cumsum(loc): tt[i]>=k+1  <=>  i >= pos[k]
// ---------------------------------------------------------------------------
__device__ __forceinline__ void find5(const int* __restrict__ loc, int b,
                                      int* posS, int tid) {
  if (tid < 64) {
    int pos[5] = {NTXT, NTXT, NTXT, NTXT, NTXT};
    int found = 0;
    for (int base = 0; base < NTXT && found < 5; base += 64) {
      unsigned long long m = __ballot(loc[b * NTXT + base + tid] != 0);
      while (m && found < 5) {
        const int p = __ffsll(m) - 1;
        pos[found++] = base + p;
        m &= m - 1;
      }
    }
    if (tid == 0) {
#pragma unroll
      for (int k = 0; k < 5; k++) posS[k] = pos[k];
    }
  }
  __syncthreads();
}

// ---------------------------------------------------------------------------
// K_A: blocks 0..1    : find5 -> seg
//      blocks 2..257  : img16 = (f16)image + ipart column partial sums
//      blocks 258..259: LayerNorm real rows -> tn; zero their out rows
//      blocks 260..275: zero qbuf | av | vbar | obar
// ---------------------------------------------------------------------------
__global__ __launch_bounds__(1024) void kA(
    const int* __restrict__ loc, const float* __restrict__ image,
    const float* __restrict__ text, const float* __restrict__ gamma,
    const float* __restrict__ beta, int* __restrict__ seg,
    float* __restrict__ ipart, _Float16* __restrict__ img16,
    float* __restrict__ tn, float* __restrict__ out,
    float* __restrict__ zbase) {
  __shared__ int posS[5];
  __shared__ float wred[20];
  const int idx = blockIdx.x;
  const int tid = threadIdx.x;
  if (idx < BATCH) {
    const int b = idx;
    find5(loc, b, posS, tid);
    if (tid == 0) {
#pragma unroll
      for (int k = 0; k < 5; k++) seg[b * 8 + k] = posS[k];
      int cnt = posS[4] - posS[0];
      if (posS[0] >= NTXT) cnt = 0;
      seg[b * 8 + 5] = min(cnt, RMAX);
    }
  } else if (idx < BATCH + 256) {
    // ---- image convert + partial column sums ----
    const int j = idx - BATCH;           // 0..255
    const int b = j >> 7, rt = j & 127;  // 128 row-tiles of 8 per batch
    const size_t base = (size_t)(b * TM + rt * 8) * DIM + tid;
    const float* p = image + base;
    _Float16* q = img16 + base;
    float s = 0.f;
#pragma unroll
    for (int r = 0; r < 8; r++) {
      const float v = p[(size_t)r * DIM];
      s += v;
      q[(size_t)r * DIM] = (_Float16)v;
    }
    ipart[(size_t)(b * 128 + rt) * DIM + tid] = s;
  } else if (idx < BATCH + 256 + 2) {
    // ---- LayerNorm of real rows + zero their out rows ----
    const int b = idx - (BATCH + 256);
    find5(loc, b, posS, tid);
    const int pos0 = posS[0];
    int cnt = posS[4] - pos0;
    if (pos0 >= NTXT) cnt = 0;
    cnt = min(cnt, RMAX);
    for (int r = 0; r < cnt; r++) {
      const float x = text[(size_t)(b * NTXT + pos0 + r) * DIM + tid];
      float v = x;
#pragma unroll
      for (int off = 32; off; off >>= 1) v += __shfl_xor(v, off, 64);
      if ((tid & 63) == 0) wred[tid >> 6] = v;
      __syncthreads();
      if (tid == 0) {
        float t2 = 0.f;
#pragma unroll
        for (int q2 = 0; q2 < 16; q2++) t2 += wred[q2];
        wred[16] = t2;
      }
      __syncthreads();
      const float mu = wred[16] * (1.0f / DIM);
      __syncthreads();
      const float d = x - mu;
      float v2 = d * d;
#pragma unroll
      for (int off = 32; off; off >>= 1) v2 += __shfl_xor(v2, off, 64);
      if ((tid & 63) == 0) wred[tid >> 6] = v2;
      __syncthreads();
      if (tid == 0) {
        float t2 = 0.f;
#pragma unroll
        for (int q2 = 0; q2 < 16; q2++) t2 += wred[q2];
        wred[16] = t2;
      }
      __syncthreads();
      const float rstd = rsqrtf(wred[16] * (1.0f / DIM) + 1e-5f);
      __syncthreads();
      tn[(size_t)(b * RMAX + r) * DIM + tid] = d * rstd * gamma[tid] + beta[tid];
      out[(size_t)(b * NTXT + pos0 + r) * DIM + tid] = 0.f;
    }
  } else {
    // ---- zero qbuf(2MB)+av(2MB)+vbar+obar = 1052672 f = 263168 float4 ----
    const int j = idx - (BATCH + 256 + 2);   // 0..15
    float4* z = reinterpret_cast<float4*>(zbase);
    const float4 zv = {0.f, 0.f, 0.f, 0.f};
    for (int i = j * 1024 + tid; i < 263168; i += 16 * 1024) z[i] = zv;
  }
}

// ---------------------------------------------------------------------------
// K_B: blocks 0..63  : Q: qbuf[r,n0:+128] += tn[r,c0:+256] @ Wq (k-split)
//      blocks 64..127: vbar = (mean img) @ Wkv_v  (k-split atomics)
// ---------------------------------------------------------------------------
__global__ __launch_bounds__(256) void kB(
    const float* __restrict__ Wq, const float* __restrict__ Wkv,
    const float* __restrict__ tn, const int* __restrict__ seg,
    const float* __restrict__ ipart, float* __restrict__ qbuf,
    float* __restrict__ vbar) {
  __shared__ float sm[2048];
  const int idx = blockIdx.x;
  const int tid = threadIdx.x;
  if (idx < 64) {
    // ---- qproj (proven round-3..7 pattern, 256 threads) ----
    float* tn_s = sm;                        // 8 rows x 256 c
    const int b = idx >> 5, nt = (idx >> 2) & 7, cc = idx & 3;
    const int n0 = nt * 128, c0 = cc * 256;
    const int n = tid & 127, cs = tid >> 7;  // 2 c-subchunks of 128
    const int cnt = seg[b * 8 + 5];
    for (int r0 = 0; r0 < cnt; r0 += 8) {
      const int nr = min(8, cnt - r0);
      for (int k = tid; k < 8 * 256; k += 256) {
        const int r = k >> 8, c = k & 255;
        tn_s[k] = (r < nr) ? tn[(size_t)(b * RMAX + r0 + r) * DIM + c0 + c]
                           : 0.f;
      }
      __syncthreads();
      float acc[8] = {};
      for (int ci = 0; ci < 128; ci++) {
        const int c = cs * 128 + ci;
        const float w = Wq[(size_t)(c0 + c) * DIM + n0 + n];
#pragma unroll
        for (int r = 0; r < 8; r++) acc[r] += tn_s[r * 256 + c] * w;
      }
#pragma unroll
      for (int r = 0; r < 8; r++)
        if (r < nr)
          atomicAdd(&qbuf[(size_t)(b * RMAX + r0 + r) * DIM + n0 + n], acc[r]);
      __syncthreads();
    }
  } else {
    // ---- vbar (proven round-6 pattern) ----
    float* red = sm;
    const int j = idx - 64;             // 0..63
    const int b = j >> 5, et = (j >> 3) & 3, cc = j & 7;
    const int e = et * 256 + tid;
    const int c0 = cc * 128;
    if (tid < 128) {
      float s = 0.f;
      for (int p = 0; p < 128; p++)
        s += ipart[(size_t)(b * 128 + p) * DIM + c0 + tid];
      red[tid] = s * (1.0f / (float)TM);
    }
    __syncthreads();
    float s = 0.f;
    for (int c = 0; c < 128; c++)
      s += red[c] * Wkv[(size_t)(c0 + c) * KVW + DIM + e];
    atomicAdd(&vbar[b * DIM + e], s);
  }
}

// ---------------------------------------------------------------------------
// K_C: blocks 0..255 : U[i,h,cc*128+c] = Q[i,h,:] @ Wk[cc*128+c,:]^T -> U16
//                      grid (b,h,cc): weight chunk LDS-stationary, no atomics
//      blocks 256..287: obar = vbar @ Wo (k-split atomics)
// ---------------------------------------------------------------------------
__global__ __launch_bounds__(256) void kC(
    const float* __restrict__ Wkv, const float* __restrict__ Wo,
    const float* __restrict__ qbuf, const float* __restrict__ vbar,
    const int* __restrict__ seg, _Float16* __restrict__ U16,
    float* __restrict__ obar) {
  __shared__ float wk_s[128][65];     // 33.3 KB, padded: conflict-free col read
  __shared__ float Qs[16][64];        // broadcast reads only
  __shared__ float vb_s[128];
  const int idx = blockIdx.x;
  const int tid = threadIdx.x;
  if (idx < 256) {
    const int b = idx >> 7, li = idx & 127;
    const int h = li >> 3, cc = li & 7;
    const int cnt = seg[b * 8 + 5];
    if (cnt == 0) return;
    // stage Wk chunk: rows cc*128..+128, cols h*64..+64 (256B/wave coalesced)
    for (int k = tid; k < 128 * 64; k += 256) {
      const int row = k >> 6, col = k & 63;
      wk_s[row][col] = Wkv[(size_t)(cc * 128 + row) * KVW + h * DHD + col];
    }
    const int c = tid & 127, g = tid >> 7;
    for (int r0 = 0; r0 < cnt; r0 += 16) {
      const int nr = min(16, cnt - r0);
      __syncthreads();
      for (int k = tid; k < 16 * 64; k += 256) {
        const int i2 = k >> 6, d = k & 63;
        Qs[i2][d] = (i2 < nr)
            ? qbuf[(size_t)(b * RMAX + r0 + i2) * DIM + h * DHD + d] : 0.f;
      }
      __syncthreads();
#pragma unroll
      for (int ii = 0; ii < 8; ii++) {
        const int i2 = g * 8 + ii;
        if (i2 < nr) {
          float u = 0.f;
#pragma unroll 16
          for (int d = 0; d < 64; d++) u += Qs[i2][d] * wk_s[c][d];
          U16[((size_t)(b * RMAX + r0 + i2) * NH + h) * DIM + cc * 128 + c] =
              (_Float16)u;
        }
      }
    }
  } else {
    // ---- obar (proven round-5 pattern) ----
    const int j = idx - 256;                 // 0..31
    const int b = j >> 4, sub = j & 15;
    const int kc = sub >> 1, eh = sub & 1;
    const int c0 = kc * 128, e0 = eh * 512;
    if (tid < 128) vb_s[tid] = vbar[b * DIM + c0 + tid];
    __syncthreads();
    float s0 = 0.f, s1 = 0.f;
    for (int ci = 0; ci < 128; ci++) {
      const float v = vb_s[ci];
      const float* wr = Wo + (size_t)(c0 + ci) * DIM + e0;
      s0 += v * wr[tid];
      s1 += v * wr[tid + 256];
    }
    atomicAdd(&obar[b * DIM + e0 + tid], s0);
    atomicAdd(&obar[b * DIM + e0 + 256 + tid], s1);
  }
}

// ---------------------------------------------------------------------------
// K_D: blocks 0..4095   : fill (i<pos0 -> zero, i>=pos4 -> obar; real skipped)
//      blocks 4096..5119: fused scores+softmax+pbar per (b,h,islot);
//                         latency-bound blocks hide among the fill blocks
// ---------------------------------------------------------------------------
__global__ __launch_bounds__(256) void kD(
    const _Float16* __restrict__ img16, const _Float16* __restrict__ U16,
    const int* __restrict__ seg, const float* __restrict__ obar,
    float* __restrict__ pbar, float* __restrict__ out) {
  __shared__ _Float16 Us[DIM];
  __shared__ float pbuf[256];
  __shared__ float wred[8];
  const int idx = blockIdx.x;
  const int tid = threadIdx.x;
  if (idx < BATCH * NTXT) {
    const int b = idx >> 11;
    const int i = idx & (NTXT - 1);
    const int p0 = seg[b * 8 + 0], p4 = seg[b * 8 + 4];
    float4* orow = reinterpret_cast<float4*>(out + (size_t)(b * NTXT + i) * DIM);
    if (i < p0) {
      const float4 zv = {0.f, 0.f, 0.f, 0.f};
      orow[tid] = zv;
    } else if (i >= p4) {
      orow[tid] = reinterpret_cast<const float4*>(obar + b * DIM)[tid];
    }
    // real rows: zeroed in kA, accumulated by kF
  } else {
    const int j = idx - BATCH * NTXT;        // 0..1023
    const int b = j >> 9, h = (j >> 5) & 15, islot = j & 31;
    const int p0 = seg[b * 8 + 0], p1 = seg[b * 8 + 1];
    const int p2 = seg[b * 8 + 2], p3 = seg[b * 8 + 3];
    const int cnt = seg[b * 8 + 5];
    const int lane = tid & 63, w = tid >> 6;
    for (int i = islot; i < cnt; i += 32) {
      const int ig = p0 + i;
      const int t = (ig >= p1) + (ig >= p2) + (ig >= p3);   // 0..3
      const int jg = b * TM + t * MMED;
      __syncthreads();   // protect Us/pbuf/wred reuse across iterations
      *reinterpret_cast<f16x4*>(Us + tid * 4) = *reinterpret_cast<const f16x4*>(
          U16 + ((size_t)(b * RMAX + i) * NH + h) * DIM + tid * 4);
      __syncthreads();
      // score for kv row jg+tid: S = U_row . img_row  (K=1024)
      const _Float16* irow = img16 + (size_t)(jg + tid) * DIM;
      float sc = 0.f;
      for (int c8 = 0; c8 < 128; c8++) {
        const f16x8 iv = *reinterpret_cast<const f16x8*>(irow + c8 * 8);
        const f16x8 uv = *reinterpret_cast<const f16x8*>(Us + c8 * 8);
#pragma unroll
        for (int u = 0; u < 8; u++) sc += (float)uv[u] * (float)iv[u];
      }
      sc *= 0.125f;
      // softmax over the 256-row mask block
      float mv = sc;
#pragma unroll
      for (int off = 32; off; off >>= 1) mv = fmaxf(mv, __shfl_xor(mv, off, 64));
      if (lane == 0) wred[w] = mv;
      __syncthreads();
      mv = fmaxf(fmaxf(wred[0], wred[1]), fmaxf(wred[2], wred[3]));
      const float e = __expf(sc - mv);
      float sv = e;
#pragma unroll
      for (int off = 32; off; off >>= 1) sv += __shfl_xor(sv, off, 64);
      if (lane == 0) wred[4 + w] = sv;
      __syncthreads();
      sv = wred[4] + wred[5] + wred[6] + wred[7];
      pbuf[tid] = e / sv;
      __syncthreads();
      // pbar[i,h,c] = sum_j p[j]*img[jg+j][c]; thread owns 4 consecutive c
      const int c0 = tid * 4;
      const _Float16* ib = img16 + (size_t)jg * DIM + c0;
      f32x4 acc = {};
      for (int j2 = 0; j2 < 256; j2++) {
        const float pj = pbuf[j2];
        const f16x4 iv = *reinterpret_cast<const f16x4*>(ib + (size_t)j2 * DIM);
        acc[0] += pj * (float)iv[0];
        acc[1] += pj * (float)iv[1];
        acc[2] += pj * (float)iv[2];
        acc[3] += pj * (float)iv[3];
      }
      *reinterpret_cast<f32x4*>(
          pbar + ((size_t)(b * RMAX + i) * NH + h) * DIM + c0) = acc;
    }
  }
}

// ---------------------------------------------------------------------------
// K_E: av[i, h*64+d] += pbar[i,h,cc*256:+256] @ Wv[cc*256:+256, h*64+d]
//      grid (b,h,cc) = 128 blocks; 16-row batches, static-unrolled acc
// ---------------------------------------------------------------------------
__global__ __launch_bounds__(256) void kE(
    const float* __restrict__ pbar, const float* __restrict__ Wkv,
    const int* __restrict__ seg, float* __restrict__ av) {
  __shared__ float pb_s[16][256];   // 16 KB
  const int idx = blockIdx.x;
  const int tid = threadIdx.x;
  const int b = idx >> 6, h = (idx >> 2) & 15, cc = idx & 3;
  const int cnt = seg[b * 8 + 5];
  if (cnt == 0) return;
  const int d = tid & 63, cg = tid >> 6;   // 4 c-subchunks of 64
  for (int r0 = 0; r0 < cnt; r0 += 16) {
    const int nr = min(16, cnt - r0);
    __syncthreads();
    for (int k = tid; k < 16 * 256; k += 256) {
      const int i2 = k >> 8, c = k & 255;
      pb_s[i2][c] = (i2 < nr)
          ? pbar[((size_t)(b * RMAX + r0 + i2) * NH + h) * DIM + cc * 256 + c]
          : 0.f;
    }
    __syncthreads();
    float acc[16] = {};
    for (int ci = 0; ci < 64; ci++) {
      const int c = cg * 64 + ci;
      const float wv = Wkv[(size_t)(cc * 256 + c) * KVW + DIM + h * DHD + d];
#pragma unroll
      for (int i2 = 0; i2 < 16; i2++) acc[i2] += pb_s[i2][c] * wv;
    }
#pragma unroll
    for (int i2 = 0; i2 < 16; i2++)
      if (i2 < nr)
        atomicAdd(&av[(size_t)(b * RMAX + r0 + i2) * DIM + h * DHD + d],
                  acc[i2]);
  }
}

// ---------------------------------------------------------------------------
// K_F: out[real i, eq*256:+256] += av[i, h*64:+64] @ Wo[h*64:+64, eq*256:+256]
//      grid (b,h,eq) = 128 blocks; Wo streamed coalesced, LDS-stationary av
// ---------------------------------------------------------------------------
__global__ __launch_bounds__(256) void kF(
    const float* __restrict__ av, const float* __restrict__ Wo,
    const int* __restrict__ seg, float* __restrict__ out) {
  __shared__ float av_s[16][64];    // 4 KB
  const int idx = blockIdx.x;
  const int tid = threadIdx.x;
  const int b = idx >> 6, h = (idx >> 2) & 15, eq = idx & 3;
  const int p0 = seg[b * 8 + 0];
  const int cnt = seg[b * 8 + 5];
  if (cnt == 0) return;
  const int e = eq * 256 + tid;
  for (int r0 = 0; r0 < cnt; r0 += 16) {
    const int nr = min(16, cnt - r0);
    __syncthreads();
    for (int k = tid; k < 16 * 64; k += 256) {
      const int i2 = k >> 6, d2 = k & 63;
      av_s[i2][d2] = (i2 < nr)
          ? av[(size_t)(b * RMAX + r0 + i2) * DIM + h * DHD + d2] : 0.f;
    }
    __syncthreads();
    float acc[16] = {};
    for (int d2 = 0; d2 < 64; d2++) {
      const float w = Wo[(size_t)(h * DHD + d2) * DIM + e];
#pragma unroll
      for (int i2 = 0; i2 < 16; i2++) acc[i2] += av_s[i2][d2] * w;
    }
#pragma unroll
    for (int i2 = 0; i2 < 16; i2++)
      if (i2 < nr)
        atomicAdd(&out[(size_t)(b * NTXT + p0 + r0 + i2) * DIM + e], acc[i2]);
  }
}

// ---------------------------------------------------------------------------
extern "C" void kernel_launch(void* const* d_in, const int* in_sizes, int n_in,
                              void* d_out, int out_size, void* d_ws, size_t ws_size,
                              hipStream_t stream) {
  const float* text  = (const float*)d_in[0];
  const float* image = (const float*)d_in[1];
  const int*   loc   = (const int*)d_in[2];
  const float* Wq    = (const float*)d_in[3];
  const float* Wkv   = (const float*)d_in[4];
  const float* Wo    = (const float*)d_in[5];
  const float* gamma = (const float*)d_in[6];
  const float* beta  = (const float*)d_in[7];
  float* out = (float*)d_out;

  // ws layout (~59 MB):
  // img16 4MB | U16 16MB | pbar 32MB | tn 2MB | ipart 1MB |
  // [kA-zeroed: qbuf 2MB | av 2MB | vbar | obar] | seg
  _Float16* img16 = (_Float16*)d_ws;
  _Float16* U16   = img16 + (size_t)BATCH * TM * DIM;
  float*    pbar  = (float*)(U16 + (size_t)BATCH * RMAX * NH * DIM);
  float*    tn    = pbar + (size_t)BATCH * RMAX * NH * DIM;
  float*    ipart = tn + (size_t)BATCH * RMAX * DIM;
  float*    qbuf  = ipart + (size_t)BATCH * 128 * DIM;
  float*    av    = qbuf + (size_t)BATCH * RMAX * DIM;
  float*    vbar  = av + (size_t)BATCH * RMAX * DIM;
  float*    obar  = vbar + BATCH * DIM;
  int*      seg   = (int*)(obar + BATCH * DIM);

  kA<<<BATCH + 256 + 2 + 16, 1024, 0, stream>>>(
      loc, image, text, gamma, beta, seg, ipart, img16, tn, out, qbuf);
  kB<<<128, 256, 0, stream>>>(Wq, Wkv, tn, seg, ipart, qbuf, vbar);
  kC<<<288, 256, 0, stream>>>(Wkv, Wo, qbuf, vbar, seg, U16, obar);
  kD<<<BATCH * NTXT + 1024, 256, 0, stream>>>(img16, U16, seg, obar, pbar, out);
  kE<<<128, 256, 0, stream>>>(pbar, Wkv, seg, av);
  kF<<<128, 256, 0, stream>>>(av, Wo, seg, out);
}

// Round 9
// 152.975 us; speedup vs baseline: 1.9019x; 1.9019x over previous
//
#include <hip/hip_runtime.h>

// Problem constants (setup_inputs is fixed)
#define BATCH 2
#define NTXT  2048
#define TMED  4
#define MMED  256
#define TM    (TMED * MMED)      // 1024 kv rows per batch
#define DIM   1024
#define NH    16
#define DHD   64
#define KVW   2048               // k|v concatenated width
#define RMAX  256                // max real rows per batch handled by fast path
#define RT    32                 // row-tile parallelism for heavy-path kernels

typedef _Float16 f16x8 __attribute__((ext_vector_type(8)));
typedef float    f32x4 __attribute__((ext_vector_type(4)));

// ---------------------------------------------------------------------------
// K1: blocks 0..1   : inclusive scan of locations -> txt_time + segment
//                     (wave-shuffle scan: 2 barriers instead of 22)
//     blocks 2..257 : img16 = (f16)image + per-block column partial sums
//     blocks 258..769: Wkv (K x N f32) -> WkvT (N x K f16) transpose
//     blocks 770..785: zero qbuf|vbar|obar (absorbs the hipMemsetAsync)
// ---------------------------------------------------------------------------
__global__ __launch_bounds__(1024) void k1_scan_cvt_tr(
    const int* __restrict__ loc, const float* __restrict__ image,
    const float* __restrict__ Wkv, int* __restrict__ tt, int* __restrict__ seg,
    float* __restrict__ ipart, _Float16* __restrict__ img16,
    _Float16* __restrict__ WkvT, float* __restrict__ zbase) {
  __shared__ float tile[64][65];
  __shared__ int wtot[16];
  __shared__ int wmin[2][16];
  const int idx = blockIdx.x;
  const int tid = threadIdx.x;
  if (idx < BATCH) {
    // ---- scan: each thread owns 2 consecutive elements ----
    const int b = idx;
    const int lane = tid & 63, w = tid >> 6;
    const int e0 = tid * 2;
    const int a0 = loc[b * NTXT + e0], a1 = loc[b * NTXT + e0 + 1];
    const int p = a0 + a1;
    int incl = p;
#pragma unroll
    for (int off = 1; off < 64; off <<= 1) {
      const int t2 = __shfl_up(incl, off, 64);
      if (lane >= off) incl += t2;
    }
    if (lane == 63) wtot[w] = incl;
    __syncthreads();
    if (tid < 16) {
      const int v = wtot[tid];
      int inc2 = v;
#pragma unroll
      for (int off = 1; off < 16; off <<= 1) {
        const int t3 = __shfl_up(inc2, off, 64);
        if (tid >= off) inc2 += t3;
      }
      wtot[tid] = inc2 - v;          // exclusive prefix for wave tid
    }
    __syncthreads();
    const int base = wtot[w] + (incl - p);
    const int t0v = base + a0, t1v = t0v + a1;
    tt[b * NTXT + e0]     = t0v;
    tt[b * NTXT + e0 + 1] = t1v;
    // first index with tt>=1 and tt>=5 (tt nondecreasing)
    {
      const int c1 = (t1v >= 1) ? ((t0v >= 1) ? e0 : e0 + 1) : NTXT;
      const int c5 = (t1v >= 5) ? ((t0v >= 5) ? e0 : e0 + 1) : NTXT;
      const unsigned long long b1 = __ballot(t1v >= 1);
      const unsigned long long b5 = __ballot(t1v >= 5);
      int m1 = NTXT, m5 = NTXT;
      if (b1) m1 = __shfl(c1, __ffsll(b1) - 1, 64);
      if (b5) m5 = __shfl(c5, __ffsll(b5) - 1, 64);
      if (lane == 0) { wmin[0][w] = m1; wmin[1][w] = m5; }
    }
    __syncthreads();
    if (tid == 0) {
      int s = NTXT, e = NTXT;
#pragma unroll
      for (int i = 0; i < 16; i++) {
        s = min(s, wmin[0][i]);
        e = min(e, wmin[1][i]);
      }
      seg[b * 2]     = s;
      seg[b * 2 + 1] = e - s;
    }
  } else if (idx < BATCH + 256) {
    // ---- image convert + partial column sums ----
    const int j = idx - BATCH;           // 0..255
    const int b = j >> 7, rt = j & 127;  // 128 row-tiles of 8 per batch
    const size_t base = (size_t)(b * TM + rt * 8) * DIM + tid;
    const float* p = image + base;
    _Float16* q = img16 + base;
    float s = 0.f;
#pragma unroll
    for (int r = 0; r < 8; r++) {
      const float v = p[(size_t)r * DIM];
      s += v;
      q[(size_t)r * DIM] = (_Float16)v;
    }
    ipart[(size_t)(b * 128 + rt) * DIM + tid] = s;
  } else if (idx < BATCH + 256 + 512) {
    // ---- transpose+convert Wkv (64x64 tiles, 1024 threads) ----
    const int j2 = idx - BATCH - 256;    // 0..511
    const int k0 = (j2 & 15) * 64, n0 = (j2 >> 4) * 64;
    const int r = tid >> 4, c4 = (tid & 15) * 4;
    const float4 v = *reinterpret_cast<const float4*>(
        Wkv + (size_t)(k0 + r) * KVW + n0 + c4);
    tile[r][c4 + 0] = v.x; tile[r][c4 + 1] = v.y;
    tile[r][c4 + 2] = v.z; tile[r][c4 + 3] = v.w;
    __syncthreads();
    if (tid < 512) {
      const int n = tid >> 3, kc = (tid & 7) * 8;
      f16x8 h;
#pragma unroll
      for (int u = 0; u < 8; u++) h[u] = (_Float16)tile[kc + u][n];
      *reinterpret_cast<f16x8*>(WkvT + (size_t)(n0 + n) * DIM + k0 + kc) = h;
    }
  } else {
    // ---- zero qbuf + vbar + obar (528384 floats = 132096 float4) ----
    const int j = idx - (BATCH + 256 + 512);   // 0..15
    float4* z = reinterpret_cast<float4*>(zbase);
    const float4 zv = {0.f, 0.f, 0.f, 0.f};
    for (int i = j * 1024 + tid; i < 132096; i += 16 * 1024) z[i] = zv;
  }
}

// ---------------------------------------------------------------------------
// K2: blocks 0..63  : LayerNorm of real rows -> tn
//     blocks 64..127: vbar[b,e] += (reduce ipart -> ibar chunk) @ Wkv_v
//     blocks 128..129: zero out[] rows of the real segment (for k4's atomics)
// ---------------------------------------------------------------------------
__global__ __launch_bounds__(256) void k2_prep(
    const float* __restrict__ Wkv, const float* __restrict__ text,
    const float* __restrict__ gamma, const float* __restrict__ beta,
    const int* __restrict__ seg, const float* __restrict__ ipart,
    float* __restrict__ tn, float* __restrict__ vbar,
    float* __restrict__ out) {
  __shared__ float red[256];
  const int idx = blockIdx.x;
  const int tid = threadIdx.x;
  if (idx < 64) {
    // ---- LayerNorm of real rows ----
    const int b = idx >> 5, rt = idx & 31;
    const int i0 = seg[b * 2];
    const int cnt = min(seg[b * 2 + 1], RMAX);
    for (int r = rt; r < cnt; r += RT) {
      const float* xrow = text + (size_t)(b * NTXT + i0 + r) * DIM;
      float x[4];
      float s = 0.f;
#pragma unroll
      for (int u = 0; u < 4; u++) { x[u] = xrow[tid + 256 * u]; s += x[u]; }
      red[tid] = s; __syncthreads();
      for (int st = 128; st > 0; st >>= 1) {
        if (tid < st) red[tid] += red[tid + st];
        __syncthreads();
      }
      const float mu = red[0] * (1.0f / DIM); __syncthreads();
      float vs = 0.f;
#pragma unroll
      for (int u = 0; u < 4; u++) { float d = x[u] - mu; vs += d * d; }
      red[tid] = vs; __syncthreads();
      for (int st = 128; st > 0; st >>= 1) {
        if (tid < st) red[tid] += red[tid + st];
        __syncthreads();
      }
      const float rstd = rsqrtf(red[0] * (1.0f / DIM) + 1e-5f); __syncthreads();
      float* trow = tn + (size_t)(b * RMAX + r) * DIM;
#pragma unroll
      for (int u = 0; u < 4; u++) {
        const int c = tid + 256 * u;
        trow[c] = (x[u] - mu) * rstd * gamma[c] + beta[c];
      }
      __syncthreads();
    }
  } else if (idx < 128) {
    // ---- vbar partial matvec (c-chunked); ibar chunk reduced from ipart ----
    const int j = idx - 64;             // 0..63
    const int b = j >> 5, et = (j >> 3) & 3, cc = j & 7;
    const int e = et * 256 + tid;
    const int c0 = cc * 128;
    if (tid < 128) {
      float s = 0.f;
      for (int p = 0; p < 128; p++)
        s += ipart[(size_t)(b * 128 + p) * DIM + c0 + tid];
      red[tid] = s * (1.0f / (float)TM);
    }
    __syncthreads();
    float s = 0.f;
    for (int c = 0; c < 128; c++)
      s += red[c] * Wkv[(size_t)(c0 + c) * KVW + DIM + e];
    atomicAdd(&vbar[b * DIM + e], s);
  } else {
    // ---- zero real-segment output rows (k4 attnh atomicAdds into them) ----
    const int b = idx - 128;
    const int i0 = seg[b * 2];
    const int cnt = min(seg[b * 2 + 1], RMAX);
    for (int r = 0; r < cnt; r++) {
      float* orow = out + (size_t)(b * NTXT + i0 + r) * DIM;
      for (int c = tid; c < DIM; c += 256) orow[c] = 0.f;
    }
  }
}

// ---------------------------------------------------------------------------
// K3: blocks 0..255  : f16 MFMA GEMM kv16 = img16 @ WkvT^T (128x128, BK=64,
//                      8 waves, XOR-swizzled LDS, register prefetch pipeline;
//                      MFMA accumulation order identical to BK=32 version)
//     blocks 256..319: qproj partials (c-chunked, r-inner FMA, atomics)
//     blocks 320..351: obar partials  (c-chunked, atomics)
// ---------------------------------------------------------------------------
__global__ __launch_bounds__(512) void k3_gemm_qproj_obar(
    const _Float16* __restrict__ img16, const _Float16* __restrict__ WkvT,
    const float* __restrict__ Wq, const float* __restrict__ Wo,
    const float* __restrict__ tn, const float* __restrict__ vbar,
    const int* __restrict__ seg, _Float16* __restrict__ kv16,
    float* __restrict__ qbuf, float* __restrict__ obar) {
  __shared__ __align__(16) char smem[32768];
  const int idx = blockIdx.x;
  const int tid = threadIdx.x;
  if (idx < 256) {
    // ---- GEMM ----
    _Float16* As = (_Float16*)smem;          // 128*64 f16 = 16 KB
    _Float16* Bs = As + 128 * 64;            // 16 KB
    const int lane = tid & 63, wid = tid >> 6;
    const int wm = wid & 3, wn = wid >> 2;
    const int row0 = (idx >> 4) * 128, col0 = (idx & 15) * 128;
    const int srow = tid >> 3, skc = (tid & 7) * 8;   // 64 rows/pass, 2 passes
    const int frow = lane & 15, fq = lane >> 4;
    const int swk = skc ^ ((srow & 7) << 3);          // f16-index XOR swizzle
    f32x4 acc[2][4] = {};
    // prologue: prefetch k0 = 0
    f16x8 a0v = *reinterpret_cast<const f16x8*>(
        img16 + (size_t)(row0 + srow) * DIM + skc);
    f16x8 a1v = *reinterpret_cast<const f16x8*>(
        img16 + (size_t)(row0 + srow + 64) * DIM + skc);
    f16x8 b0v = *reinterpret_cast<const f16x8*>(
        WkvT + (size_t)(col0 + srow) * DIM + skc);
    f16x8 b1v = *reinterpret_cast<const f16x8*>(
        WkvT + (size_t)(col0 + srow + 64) * DIM + skc);
    for (int k0 = 0; k0 < DIM; k0 += 64) {
      __syncthreads();   // previous iteration's ds_reads done
      *reinterpret_cast<f16x8*>(As + srow * 64 + swk)        = a0v;
      *reinterpret_cast<f16x8*>(As + (srow + 64) * 64 + swk) = a1v;
      *reinterpret_cast<f16x8*>(Bs + srow * 64 + swk)        = b0v;
      *reinterpret_cast<f16x8*>(Bs + (srow + 64) * 64 + swk) = b1v;
      __syncthreads();
      if (k0 + 64 < DIM) {   // prefetch next slab; latency hides under MFMA
        a0v = *reinterpret_cast<const f16x8*>(
            img16 + (size_t)(row0 + srow) * DIM + k0 + 64 + skc);
        a1v = *reinterpret_cast<const f16x8*>(
            img16 + (size_t)(row0 + srow + 64) * DIM + k0 + 64 + skc);
        b0v = *reinterpret_cast<const f16x8*>(
            WkvT + (size_t)(col0 + srow) * DIM + k0 + 64 + skc);
        b1v = *reinterpret_cast<const f16x8*>(
            WkvT + (size_t)(col0 + srow + 64) * DIM + k0 + 64 + skc);
      }
      f16x8 af[2][2], bf[2][4];
#pragma unroll
      for (int kk = 0; kk < 2; kk++) {
#pragma unroll
        for (int mt = 0; mt < 2; mt++) {
          const int r = wm * 32 + mt * 16 + frow;
          af[kk][mt] = *reinterpret_cast<const f16x8*>(
              As + r * 64 + ((kk * 32 + fq * 8) ^ ((r & 7) << 3)));
        }
#pragma unroll
        for (int nt = 0; nt < 4; nt++) {
          const int c = wn * 64 + nt * 16 + frow;
          bf[kk][nt] = *reinterpret_cast<const f16x8*>(
              Bs + c * 64 + ((kk * 32 + fq * 8) ^ ((c & 7) << 3)));
        }
      }
#pragma unroll
      for (int kk = 0; kk < 2; kk++)
#pragma unroll
        for (int mt = 0; mt < 2; mt++)
#pragma unroll
          for (int nt = 0; nt < 4; nt++)
            acc[mt][nt] = __builtin_amdgcn_mfma_f32_16x16x32_f16(
                af[kk][mt], bf[kk][nt], acc[mt][nt], 0, 0, 0);
    }
#pragma unroll
    for (int mt = 0; mt < 2; mt++)
#pragma unroll
      for (int nt = 0; nt < 4; nt++) {
        const int col = col0 + wn * 64 + nt * 16 + frow;
#pragma unroll
        for (int r = 0; r < 4; r++) {
          const int row = row0 + wm * 32 + mt * 16 + fq * 4 + r;
          kv16[(size_t)row * KVW + col] = (_Float16)acc[mt][nt][r];
        }
      }
  } else if (idx < 320) {
    // ---- qproj: q[r, n0:n0+128] += tn[r, c0:c0+256] @ Wq[c0:c0+256, n] ----
    float* tn_s = (float*)smem;              // 8 rows x 256 c = 8 KB
    const int j = idx - 256;                 // 0..63
    const int b = j >> 5, nt = (j >> 2) & 7, cc = j & 3;
    const int n0 = nt * 128, c0 = cc * 256;
    const int n = tid & 127, cs = tid >> 7;  // 4 c-subchunks of 64
    const int cnt = min(seg[b * 2 + 1], RMAX);
    for (int r0 = 0; r0 < cnt; r0 += 8) {
      const int rows = min(8, cnt - r0);
      for (int i = tid; i < 8 * 256; i += 512) {
        const int r = i >> 8, c = i & 255;
        tn_s[i] = (r < rows) ? tn[(size_t)(b * RMAX + r0 + r) * DIM + c0 + c]
                             : 0.f;
      }
      __syncthreads();
      float acc[8] = {};
      for (int ci = 0; ci < 64; ci++) {
        const int c = cs * 64 + ci;
        const float w = Wq[(size_t)(c0 + c) * DIM + n0 + n];
#pragma unroll
        for (int rr = 0; rr < 8; rr++) acc[rr] += tn_s[rr * 256 + c] * w;
      }
      for (int rr = 0; rr < rows; rr++)
        atomicAdd(&qbuf[(size_t)(b * RMAX + r0 + rr) * DIM + n0 + n], acc[rr]);
      __syncthreads();
    }
  } else {
    // ---- obar: obar[b,e] += vbar[b, c0:c0+128] @ Wo[c0:c0+128, e] ----
    float* vb_s = (float*)smem;              // 128 f32
    const int j = idx - 320;                 // 0..31
    const int b = j >> 4, et = (j >> 3) & 1, cc = j & 7;
    const int e = et * 512 + tid;
    const int c0 = cc * 128;
    if (tid < 128) vb_s[tid] = vbar[b * DIM + c0 + tid];
    __syncthreads();
    float s = 0.f;
    for (int c = 0; c < 128; c++)
      s += vb_s[c] * Wo[(size_t)(c0 + c) * DIM + e];
    atomicAdd(&obar[b * DIM + e], s);
  }
}

// ---------------------------------------------------------------------------
// K4: blocks 0..4095    : fill (zero / obar / fallback)
//     blocks 4096..5119 : attnh (q from qbuf, scores, softmax, PV,
//                         fused per-head oproj -> atomicAdd into out)
// ---------------------------------------------------------------------------
__global__ __launch_bounds__(256) void k4_fill_attn(
    const float* __restrict__ text, const _Float16* __restrict__ kv16,
    const float* __restrict__ Wq, const float* __restrict__ Wo,
    const float* __restrict__ gamma, const float* __restrict__ beta,
    const int* __restrict__ tt, const int* __restrict__ seg,
    const float* __restrict__ obar, const float* __restrict__ qbuf,
    float* __restrict__ out) {
  __shared__ float red[256];
  __shared__ float pbuf[256];
  const int idx = blockIdx.x;
  const int tid = threadIdx.x;
  if (idx < BATCH * NTXT) {
    const int b = idx >> 11;
    const int i = idx & (NTXT - 1);
    const int t = tt[b * NTXT + i];
    float* orow = out + (size_t)(b * NTXT + i) * DIM;
    if (t == 0) {
      for (int c = tid; c < DIM; c += 256) orow[c] = 0.f;
      return;
    }
    if (t > TMED) {
      const float* ob = obar + b * DIM;
      for (int c = tid; c < DIM; c += 256) orow[c] = ob[c];
      return;
    }
    if (i - seg[b * 2] < RMAX) return;
    // ---- slow fallback (unreachable for realistic data) ----
    __shared__ float tns[DIM];
    __shared__ float qrow[DIM];
    __shared__ float oaccs[DIM];
    const float* xrow = text + (size_t)(b * NTXT + i) * DIM;
    float x[4];
    float s = 0.f;
#pragma unroll
    for (int u = 0; u < 4; u++) { x[u] = xrow[tid + 256 * u]; s += x[u]; }
    red[tid] = s; __syncthreads();
    for (int st = 128; st > 0; st >>= 1) {
      if (tid < st) red[tid] += red[tid + st];
      __syncthreads();
    }
    const float mu = red[0] * (1.0f / DIM); __syncthreads();
    float vs = 0.f;
#pragma unroll
    for (int u = 0; u < 4; u++) { float d = x[u] - mu; vs += d * d; }
    red[tid] = vs; __syncthreads();
    for (int st = 128; st > 0; st >>= 1) {
      if (tid < st) red[tid] += red[tid + st];
      __syncthreads();
    }
    const float rstd = rsqrtf(red[0] * (1.0f / DIM) + 1e-5f); __syncthreads();
#pragma unroll
    for (int u = 0; u < 4; u++) {
      const int c = tid + 256 * u;
      tns[c] = (x[u] - mu) * rstd * gamma[c] + beta[c];
    }
    __syncthreads();
    {
      float qa[4] = {0.f, 0.f, 0.f, 0.f};
      for (int c = 0; c < DIM; c++) {
        const float tv = tns[c];
        const float* w = Wq + (size_t)c * DIM + tid;
#pragma unroll
        for (int u = 0; u < 4; u++) qa[u] += tv * w[256 * u];
      }
#pragma unroll
      for (int u = 0; u < 4; u++) qrow[tid + 256 * u] = qa[u];
    }
    __syncthreads();
    const size_t kvrow0 = (size_t)(b * TM + (t - 1) * MMED) * KVW;
    const int d0 = tid & 63, g = tid >> 6;
    for (int h = 0; h < NH; h++) {
      const _Float16* krow = kv16 + kvrow0 + (size_t)tid * KVW + h * DHD;
      float sc = 0.f;
#pragma unroll
      for (int d = 0; d < DHD; d++) sc += qrow[h * DHD + d] * (float)krow[d];
      sc *= 0.125f;
      red[tid] = sc; __syncthreads();
      for (int st = 128; st > 0; st >>= 1) {
        if (tid < st) red[tid] = fmaxf(red[tid], red[tid + st]);
        __syncthreads();
      }
      const float mx = red[0]; __syncthreads();
      const float e = __expf(sc - mx);
      red[tid] = e; __syncthreads();
      for (int st = 128; st > 0; st >>= 1) {
        if (tid < st) red[tid] += red[tid + st];
        __syncthreads();
      }
      const float inv = 1.0f / red[0]; __syncthreads();
      pbuf[tid] = e * inv; __syncthreads();
      const _Float16* vbase = kv16 + kvrow0 + (size_t)(g * 64) * KVW + DIM + h * DHD + d0;
      float a = 0.f;
#pragma unroll 8
      for (int jj = 0; jj < 64; jj++) a += pbuf[g * 64 + jj] * (float)vbase[(size_t)jj * KVW];
      red[tid] = a; __syncthreads();
      if (tid < 64)
        oaccs[h * DHD + tid] = red[tid] + red[64 + tid] + red[128 + tid] + red[192 + tid];
      __syncthreads();
    }
    float oa[4] = {0.f, 0.f, 0.f, 0.f};
    for (int c = 0; c < DIM; c++) {
      const float ov = oaccs[c];
      const float* w = Wo + (size_t)c * DIM + tid;
#pragma unroll
      for (int u = 0; u < 4; u++) oa[u] += ov * w[256 * u];
    }
#pragma unroll
    for (int u = 0; u < 4; u++) orow[tid + 256 * u] = oa[u];
  } else {
    // ---- attnh with fused per-head output projection ----
    __shared__ float qs[DHD];
    __shared__ float osl[DHD];
    const int j = idx - BATCH * NTXT;       // 0..1023
    const int h = j & 15, rt = (j >> 4) & 31, b = j >> 9;
    const int i0 = seg[b * 2];
    const int cnt = min(seg[b * 2 + 1], RMAX);
    const int d0 = tid & 63, g = tid >> 6;
    for (int r = rt; r < cnt; r += RT) {
      const int i = i0 + r;
      const int t = tt[b * NTXT + i];       // in [1, TMED]
      if (tid < 64) qs[tid] = qbuf[(size_t)(b * RMAX + r) * DIM + h * DHD + tid];
      __syncthreads();
      const size_t kvrow0 = (size_t)(b * TM + (t - 1) * MMED) * KVW;
      const _Float16* krow = kv16 + kvrow0 + (size_t)tid * KVW + h * DHD;
      float sc = 0.f;
#pragma unroll
      for (int d = 0; d < DHD; d += 8) {
        const f16x8 kk = *reinterpret_cast<const f16x8*>(krow + d);
#pragma unroll
        for (int u = 0; u < 8; u++) sc += qs[d + u] * (float)kk[u];
      }
      sc *= 0.125f;
      red[tid] = sc; __syncthreads();
      for (int st = 128; st > 0; st >>= 1) {
        if (tid < st) red[tid] = fmaxf(red[tid], red[tid + st]);
        __syncthreads();
      }
      const float mx = red[0]; __syncthreads();
      const float e = __expf(sc - mx);
      red[tid] = e; __syncthreads();
      for (int st = 128; st > 0; st >>= 1) {
        if (tid < st) red[tid] += red[tid + st];
        __syncthreads();
      }
      const float inv = 1.0f / red[0]; __syncthreads();
      pbuf[tid] = e * inv; __syncthreads();
      const _Float16* vbase = kv16 + kvrow0 + (size_t)(g * 64) * KVW + DIM + h * DHD + d0;
      float a = 0.f;
#pragma unroll 8
      for (int jj = 0; jj < 64; jj++) a += pbuf[g * 64 + jj] * (float)vbase[(size_t)jj * KVW];
      red[tid] = a; __syncthreads();
      if (tid < 64)
        osl[tid] = red[tid] + red[64 + tid] + red[128 + tid] + red[192 + tid];
      __syncthreads();
      // fused partial oproj: out[i,:] += osl @ Wo[h*64 : h*64+64, :]
      float* orow = out + (size_t)(b * NTXT + i) * DIM;
#pragma unroll
      for (int u = 0; u < 4; u++) {
        const int c = tid + 256 * u;
        const float* w = Wo + (size_t)(h * DHD) * DIM + c;
        float s2 = 0.f;
#pragma unroll 8
        for (int d = 0; d < DHD; d++) s2 += osl[d] * w[(size_t)d * DIM];
        atomicAdd(&orow[c], s2);
      }
      __syncthreads();
    }
  }
}

// ---------------------------------------------------------------------------
extern "C" void kernel_launch(void* const* d_in, const int* in_sizes, int n_in,
                              void* d_out, int out_size, void* d_ws, size_t ws_size,
                              hipStream_t stream) {
  const float* text  = (const float*)d_in[0];
  const float* image = (const float*)d_in[1];
  const int*   loc   = (const int*)d_in[2];
  const float* Wq    = (const float*)d_in[3];
  const float* Wkv   = (const float*)d_in[4];
  const float* Wo    = (const float*)d_in[5];
  const float* gamma = (const float*)d_in[6];
  const float* beta  = (const float*)d_in[7];
  float* out = (float*)d_out;

  // ws layout: kv16 8MB | WkvT 4MB | img16 4MB | tn 2MB |
  //            [k1-zeroed: qbuf 2MB | vbar | obar] | tt | seg | ipart 1MB
  _Float16* kv16  = (_Float16*)d_ws;
  _Float16* WkvT  = kv16 + (size_t)BATCH * TM * KVW;
  _Float16* img16 = WkvT + (size_t)KVW * DIM;
  float*    tn    = (float*)(img16 + (size_t)BATCH * TM * DIM);
  float*    qbuf  = tn + (size_t)BATCH * RMAX * DIM;
  float*    vbar  = qbuf + (size_t)BATCH * RMAX * DIM;
  float*    obar  = vbar + BATCH * DIM;
  int*      tt    = (int*)(obar + BATCH * DIM);
  int*      seg   = tt + BATCH * NTXT;
  float*    ipart = (float*)(seg + 8);                 // 256*1024 f32 = 1MB

  k1_scan_cvt_tr<<<BATCH + 256 + 512 + 16, 1024, 0, stream>>>(
      loc, image, Wkv, tt, seg, ipart, img16, WkvT, qbuf);
  k2_prep<<<130, 256, 0, stream>>>(Wkv, text, gamma, beta, seg, ipart,
                                   tn, vbar, out);
  k3_gemm_qproj_obar<<<352, 512, 0, stream>>>(img16, WkvT, Wq, Wo, tn, vbar,
                                              seg, kv16, qbuf, obar);
  k4_fill_attn<<<BATCH * NTXT + NH * RT * BATCH, 256, 0, stream>>>(
      text, kv16, Wq, Wo, gamma, beta, tt, seg, obar, qbuf, out);
}